// Round 1
// baseline (471.327 us; speedup 1.0000x reference)
//
#include <hip/hip_runtime.h>
#include <hip/hip_bf16.h>
#include <math.h>

#define V     8000
#define D_    300
#define B_    128
#define L_    300
#define C_    54
#define CHUNK 16
#define STR   17   // padded LDS row stride (17*4 bytes -> stride 17 mod 32 banks, conflict-free)

// ---------------- Kernel 1: gather edge weights ----------------
// w_ws layout: [B][L*8] (o padded 7->8)
__global__ __launch_bounds__(256) void wgather_kernel(
    const float* __restrict__ edge_w,
    const int*   __restrict__ docs,
    const int*   __restrict__ edges_matrix,
    float* __restrict__ w_ws)
{
    int idx = blockIdx.x * 256 + threadIdx.x;
    if (idx >= B_ * L_ * 7) return;
    int b   = idx / (L_ * 7);
    int rem = idx % (L_ * 7);
    int l   = rem / 7;
    int o   = rem % 7;
    int d1 = docs[b * L_ + l];
    int nb = l + o - 3;
    nb = min(max(nb, 0), L_ - 1);
    int d2 = docs[b * L_ + nb];
    int eid = edges_matrix[(size_t)d1 * V + d2];
    w_ws[b * (L_ * 8) + l * 8 + o] = edge_w[eid];
}

// ---------------- Kernel 2: h0 gather + T=2 propagation + pooled sum ----------------
// grid: (num_chunks, B), block: 256
__global__ __launch_bounds__(256) void prop_kernel(
    const float* __restrict__ node_embed,
    const float* __restrict__ node_eta,
    const float* __restrict__ w_ws,
    const int*   __restrict__ docs,
    float* __restrict__ pooled)   // [B][D]
{
    int b  = blockIdx.y;
    int d0 = blockIdx.x * CHUNK;
    int tid = threadIdx.x;

    __shared__ float h_s[2][L_ * STR];   // 2*300*17*4 = 40800 B
    __shared__ float w_s[L_ * 8];        // 9600 B
    __shared__ float eta_s[L_];          // 1200 B
    __shared__ int   docs_s[L_];         // 1200 B
    __shared__ float red[16 * 16];       // 1024 B

    for (int l = tid; l < L_; l += 256) {
        int dc = docs[b * L_ + l];
        docs_s[l] = dc;
        eta_s[l]  = node_eta[dc];
    }
    for (int i = tid; i < L_ * 8; i += 256)
        w_s[i] = w_ws[b * (L_ * 8) + i];
    __syncthreads();

    int nc = min(CHUNK, D_ - d0);

    // load h0 chunk: element e -> (l = e>>4, dd = e&15)
    for (int e = tid; e < L_ * CHUNK; e += 256) {
        int l = e >> 4, dd = e & 15;
        float v = 0.f;
        if (dd < nc) v = node_embed[(size_t)docs_s[l] * D_ + d0 + dd];
        h_s[0][l * STR + dd] = v;
    }
    __syncthreads();

    int cur = 0;
    for (int step = 0; step < 2; ++step) {
        for (int e = tid; e < L_ * CHUNK; e += 256) {
            int l = e >> 4, dd = e & 15;
            float msg = -3.402823466e38f;
            #pragma unroll
            for (int o = 0; o < 7; ++o) {
                int nb = l + o - 3;
                if ((unsigned)nb < (unsigned)L_) {
                    float cand = w_s[l * 8 + o] * h_s[cur][nb * STR + dd];
                    msg = fmaxf(msg, cand);
                }
            }
            float et = eta_s[l];
            float hv = h_s[cur][l * STR + dd];
            h_s[1 - cur][l * STR + dd] = et * hv + (1.f - et) * msg;
        }
        __syncthreads();
        cur = 1 - cur;
    }

    // pooled[b, d0+dd] = sum_l h[l][dd]
    int dd  = tid & 15;
    int grp = tid >> 4;   // 16 groups
    float part = 0.f;
    for (int l = grp; l < L_; l += 16)
        part += h_s[cur][l * STR + dd];
    red[grp * 16 + dd] = part;
    __syncthreads();
    if (tid < 16) {
        float s = 0.f;
        #pragma unroll
        for (int g = 0; g < 16; ++g) s += red[g * 16 + dd];
        if (dd < nc) pooled[b * D_ + d0 + dd] = s;
    }
}

// ---------------- Kernel 3: relu + batchnorm over batch axis ----------------
// grid: D blocks, block: 128 (one thread per b)
__global__ __launch_bounds__(128) void bn_kernel(
    const float* __restrict__ pooled,
    const float* __restrict__ gamma,
    const float* __restrict__ beta,
    float* __restrict__ xn)
{
    int d = blockIdx.x;
    int b = threadIdx.x;
    float x = fmaxf(pooled[b * D_ + d], 0.f);

    float v1 = x, v2 = x * x;
    #pragma unroll
    for (int off = 32; off > 0; off >>= 1) {
        v1 += __shfl_down(v1, off, 64);
        v2 += __shfl_down(v2, off, 64);
    }
    __shared__ float s1[2], s2[2];
    int lane = b & 63, wv = b >> 6;
    if (lane == 0) { s1[wv] = v1; s2[wv] = v2; }
    __syncthreads();
    float mean = (s1[0] + s1[1]) * (1.f / 128.f);
    float var  = (s2[0] + s2[1]) * (1.f / 128.f) - mean * mean;
    float xh = (x - mean) / sqrtf(var + 1e-5f);
    xn[b * D_ + d] = xh * gamma[d] + beta[d];
}

// ---------------- Kernel 4: matmul + bias + sigmoid ----------------
// grid: B blocks, block: 64 (thread c computes out[b,c])
__global__ __launch_bounds__(64) void out_kernel(
    const float* __restrict__ xn,
    const float* __restrict__ Wm,
    const float* __restrict__ bias,
    float* __restrict__ out)
{
    int b = blockIdx.x;
    int c = threadIdx.x;
    if (c >= C_) return;
    float acc = bias[c];
    for (int k = 0; k < D_; ++k)
        acc = fmaf(xn[b * D_ + k], Wm[k * C_ + c], acc);
    out[b * C_ + c] = 1.f / (1.f + expf(-acc));
}

extern "C" void kernel_launch(void* const* d_in, const int* in_sizes, int n_in,
                              void* d_out, int out_size, void* d_ws, size_t ws_size,
                              hipStream_t stream) {
    const float* node_embed   = (const float*)d_in[0];
    const float* node_eta     = (const float*)d_in[1];
    const float* edge_w       = (const float*)d_in[2];
    const float* bn_gamma     = (const float*)d_in[3];
    const float* bn_beta      = (const float*)d_in[4];
    const float* Wm           = (const float*)d_in[5];
    const float* bias         = (const float*)d_in[6];
    const int*   docs         = (const int*)d_in[7];
    const int*   edges_matrix = (const int*)d_in[8];
    float* out = (float*)d_out;

    // workspace layout
    float* w_ws   = (float*)d_ws;                       // B*L*8 floats = 1,228,800 B
    float* pooled = w_ws + (size_t)B_ * L_ * 8;         // B*D floats  =   153,600 B
    float* xn     = pooled + (size_t)B_ * D_;           // B*D floats  =   153,600 B

    // 1. edge-weight gather
    {
        int total = B_ * L_ * 7;
        int blocks = (total + 255) / 256;
        wgather_kernel<<<blocks, 256, 0, stream>>>(edge_w, docs, edges_matrix, w_ws);
    }
    // 2. propagation
    {
        dim3 grid((D_ + CHUNK - 1) / CHUNK, B_);  // (19, 128)
        prop_kernel<<<grid, 256, 0, stream>>>(node_embed, node_eta, w_ws, docs, pooled);
    }
    // 3. batchnorm
    bn_kernel<<<D_, 128, 0, stream>>>(pooled, bn_gamma, bn_beta, xn);
    // 4. output
    out_kernel<<<B_, 64, 0, stream>>>(xn, Wm, bias, out);
}